// Round 10
// baseline (198.840 us; speedup 1.0000x reference)
//
#include <hip/hip_runtime.h>
#include <hip/hip_bf16.h>
#include <math.h>

#define N_PTS 8192
#define S_PTS 4096
typedef unsigned long long u64;
typedef unsigned u32;

// Double-precision pair distance, rounded to float (accurate output values).
__device__ __forceinline__ float pair_dist_d(const float4 a, const float4 b) {
    double ax = a.x, ay = a.y, az = a.z;
    double bx = b.x, by = b.y, bz = b.z;
    double dx = ax - bx, dy = ay - by, dz = az - bz;
    double d2 = dx * dx + dy * dy + dz * dz;
    return d2 > 0.0 ? (float)sqrt(d2) : 0.0f;
}

// Strict fp32 gram-formula d^2 (bit-identical to the reference cdist pipeline).
__device__ __forceinline__ float d2_f32_gram(const float4 a, const float4 b) {
    float dot = __fadd_rn(__fadd_rn(__fmul_rn(a.x, b.x), __fmul_rn(a.y, b.y)),
                          __fmul_rn(a.z, b.z));
    float d2 = __fsub_rn(__fadd_rn(a.w, b.w), __fmul_rn(2.0f, dot));
    return fmaxf(d2, 0.0f);
}

__device__ __forceinline__ u32 bitonic64_u32(u32 v, int lane) {
#pragma unroll
    for (int k = 2; k <= 64; k <<= 1) {
#pragma unroll
        for (int j2 = k >> 1; j2 >= 1; j2 >>= 1) {
            u32 o = __shfl_xor(v, j2, 64);
            bool keepMin = (((lane & j2) == 0) == ((lane & k) == 0));
            bool less = o < v;
            v = keepMin ? (less ? o : v) : (less ? v : o);
        }
    }
    return v;
}

__device__ __forceinline__ u64 bitonic64_u64(u64 v, int lane) {
#pragma unroll
    for (int k = 2; k <= 64; k <<= 1) {
#pragma unroll
        for (int j2 = k >> 1; j2 >= 1; j2 >>= 1) {
            u64 o = __shfl_xor(v, j2, 64);
            bool keepMin = (((lane & j2) == 0) == ((lane & k) == 0));
            bool less = o < v;
            v = keepMin ? (less ? o : v) : (less ? v : o);
        }
    }
    return v;
}

// ---------------------------------------------------------------- stage
__global__ __launch_bounds__(256) void stage_kernel(
        const float* __restrict__ xyz, const int* __restrict__ sidx,
        float4* __restrict__ cb, float4* __restrict__ ca,
        int* __restrict__ inv, float* __restrict__ out_xyz_s) {
    int i = blockIdx.x * blockDim.x + threadIdx.x;
    if (i < N_PTS) {
        float x = xyz[i * 3 + 0], y = xyz[i * 3 + 1], z = xyz[i * 3 + 2];
        float sq = __fadd_rn(__fadd_rn(__fmul_rn(x, x), __fmul_rn(y, y)),
                             __fmul_rn(z, z));
        cb[i] = make_float4(x, y, z, sq);
    }
    if (i < S_PTS) {
        int si = sidx[i];
        float x = xyz[si * 3 + 0], y = xyz[si * 3 + 1], z = xyz[si * 3 + 2];
        float sq = __fadd_rn(__fadd_rn(__fmul_rn(x, x), __fmul_rn(y, y)),
                             __fmul_rn(z, z));
        ca[i] = make_float4(x, y, z, sq);
        inv[si] = i;  // inv pre-set to -1 by hipMemsetAsync(0xFF)
        out_xyz_s[i * 3 + 0] = x;
        out_xyz_s[i * 3 + 1] = y;
        out_xyz_s[i * 3 + 2] = z;
    }
}

// ---------------------------------------------------------------- knn cold fallbacks
// AFTER=false: top-K over all cb, key low = cb index.
// AFTER=true: top-K over sampled (inv[c]>=0), key low = ca index.
template <int K, bool AFTER>
__device__ u64 cold_ladder(const float4 q, const float4* __restrict__ cb,
                           const int* __restrict__ inv, int lane) {
    u64 L[K];
#pragma unroll
    for (int j = 0; j < K; ++j) L[j] = ~0ull;
    for (int c = lane; c < N_PTS; c += 64) {
        int low = c;
        bool ok = true;
        if (AFTER) { int iv = inv[c]; ok = iv >= 0; low = iv; }
        if (!ok) continue;
        float d2 = d2_f32_gram(q, cb[c]);
        float D = d2 > 0.0f ? __fsqrt_rn(d2) : 0.0f;
        u64 key = ((u64)__float_as_uint(D) << 32) | (u64)(u32)low;
        if (key < L[K - 1]) {
#pragma unroll
            for (int j = K - 1; j >= 1; --j)
                L[j] = (key < L[j - 1]) ? L[j - 1] : ((key < L[j]) ? key : L[j]);
            L[0] = (key < L[0]) ? key : L[0];
        }
    }
    u64 res = ~0ull;
#pragma unroll
    for (int r = 0; r < K; ++r) {
        u64 m = L[0];
#pragma unroll
        for (int off = 32; off >= 1; off >>= 1) {
            u64 o = __shfl_xor(m, off, 64);
            m = (o < m) ? o : m;
        }
        if (lane == r) res = m;
        if (L[0] == m) {
#pragma unroll
            for (int j = 0; j < K - 1; ++j) L[j] = L[j + 1];
            L[K - 1] = ~0ull;
        }
    }
    return res;
}

// sort collected candidates (cnt <= 256), lane r gets rank r
template <int K>
__device__ u64 finalize_sort(const u64* buf, u32 cnt, int lane) {
    if (cnt <= 64u) {
        u64 v = (lane < (int)cnt) ? buf[lane] : ~0ull;
        return bitonic64_u64(v, lane);
    }
    u64 L0 = ~0ull, L1 = ~0ull, L2 = ~0ull, L3 = ~0ull;
    for (u32 mm = lane; mm < cnt; mm += 64) {
        u64 kk = buf[mm];
        if (kk < L3) {
            if (kk < L1) {
                L3 = L2; L2 = L1;
                if (kk < L0) { L1 = L0; L0 = kk; } else L1 = kk;
            } else {
                if (kk < L2) { L3 = L2; L2 = kk; } else L3 = kk;
            }
        }
    }
    u64 res = ~0ull;
#pragma unroll
    for (int r = 0; r < K; ++r) {
        u64 mr = L0;
#pragma unroll
        for (int off = 32; off >= 1; off >>= 1) {
            u64 o = __shfl_xor(mr, off, 64);
            mr = (o < mr) ? o : mr;
        }
        if (lane == r) res = mr;
        if (L0 == mr) { L0 = L1; L1 = L2; L2 = L3; L3 = ~0ull; }
    }
    return res;
}

// ---------------------------------------------------------------- knn: 2 queries per block, single scan of cb
// Selection exact by (fp32-gram D, idx); tau = K-th smallest of 64 folded
// lane-minima (provable superset bound). Waves 0..3 sort the 4 streams
// (before-q0, before-q1, after-q0, after-q1) concurrently.
__global__ __launch_bounds__(256, 4) void knn_kernel(
        const float4* __restrict__ cb, const float4* __restrict__ ca,
        const int* __restrict__ inv, const int* __restrict__ sidx,
        int* __restrict__ a_before, float* __restrict__ intra_before,
        int* __restrict__ ni_i, float* __restrict__ intra_after,
        float* __restrict__ out_ni) {
    __shared__ u32 smin[4][256];  // 0:all-q0 1:all-q1 2:smp-q0 3:smp-q1
    __shared__ u64 sbuf[4][256];  // 0:b-q0 1:b-q1 2:a-q0 3:a-q1
    __shared__ u32 staus[4];
    __shared__ u32 stot[2][4];
    int t = threadIdx.x, lane = t & 63, wid = t >> 6;
    int s0 = blockIdx.x * 2, s1 = s0 + 1;
    float4 q0 = cb[sidx[s0]], q1 = cb[sidx[s1]];

    u32 d20[32], d21[32], msk = 0;
    u32 mnA0 = ~0u, mnA1 = ~0u, mnS0 = ~0u, mnS1 = ~0u;
#pragma unroll
    for (int j = 0; j < 32; ++j) {
        int c = t + 256 * j;
        float4 p = cb[c];
        u32 b0 = __float_as_uint(d2_f32_gram(q0, p));
        u32 b1 = __float_as_uint(d2_f32_gram(q1, p));
        d20[j] = b0; d21[j] = b1;
        bool smp = inv[c] >= 0;
        msk |= (u32)smp << j;
        mnA0 = b0 < mnA0 ? b0 : mnA0;
        mnA1 = b1 < mnA1 ? b1 : mnA1;
        mnS0 = (smp && b0 < mnS0) ? b0 : mnS0;
        mnS1 = (smp && b1 < mnS1) ? b1 : mnS1;
    }
    smin[0][t] = mnA0; smin[1][t] = mnA1; smin[2][t] = mnS0; smin[3][t] = mnS1;
    __syncthreads();
    {   // each wave computes its tau
        u32 v = smin[wid][lane];
        u32 v2 = smin[wid][lane + 64];  v = v2 < v ? v2 : v;
        v2 = smin[wid][lane + 128];     v = v2 < v ? v2 : v;
        v2 = smin[wid][lane + 192];     v = v2 < v ? v2 : v;
        v = bitonic64_u32(v, lane);
        int kk = (wid < 2) ? 3 : 15;    // K-1
        if (lane == kk) staus[wid] = v;
    }
    __syncthreads();
    u32 tb0 = staus[0], tb1 = staus[1], ta0 = staus[2], ta1 = staus[3];
    // counts per query: (cnt_before << 16) | cnt_after
    u32 p0 = 0, p1 = 0;
#pragma unroll
    for (int j = 0; j < 32; ++j) {
        u32 sm = (msk >> j) & 1u;
        p0 += ((d20[j] <= tb0) ? 0x10000u : 0u) + ((sm && d20[j] <= ta0) ? 1u : 0u);
        p1 += ((d21[j] <= tb1) ? 0x10000u : 0u) + ((sm && d21[j] <= ta1) ? 1u : 0u);
    }
    u32 x0 = p0, x1 = p1;
#pragma unroll
    for (int off = 1; off < 64; off <<= 1) {
        u32 y0 = __shfl_up(x0, off, 64);
        u32 y1 = __shfl_up(x1, off, 64);
        if (lane >= off) { x0 += y0; x1 += y1; }
    }
    if (lane == 63) { stot[0][wid] = x0; stot[1][wid] = x1; }
    __syncthreads();
    u32 b0s = x0 - p0, b1s = x1 - p1;
    for (int w = 0; w < wid; ++w) { b0s += stot[0][w]; b1s += stot[1][w]; }
    u32 tot0 = stot[0][0] + stot[0][1] + stot[0][2] + stot[0][3];
    u32 tot1 = stot[1][0] + stot[1][1] + stot[1][2] + stot[1][3];
    u32 cntB0 = tot0 >> 16, cntA0 = tot0 & 0xFFFFu;
    u32 cntB1 = tot1 >> 16, cntA1 = tot1 & 0xFFFFu;
    u32 ob0 = b0s >> 16, oa0 = b0s & 0xFFFFu;
    u32 ob1 = b1s >> 16, oa1 = b1s & 0xFFFFu;
#pragma unroll
    for (int j = 0; j < 32; ++j) {
        int c = t + 256 * j;
        u32 sm = (msk >> j) & 1u;
        bool qb0 = d20[j] <= tb0, qa0 = sm && d20[j] <= ta0;
        if (qb0 || qa0) {
            float d2v = __uint_as_float(d20[j]);
            float D = d2v > 0.0f ? __fsqrt_rn(d2v) : 0.0f;
            u64 hk = (u64)__float_as_uint(D) << 32;
            if (qb0 && cntB0 <= 256u) sbuf[0][ob0++] = hk | (u64)(u32)c;
            if (qa0 && cntA0 <= 256u) sbuf[2][oa0++] = hk | (u64)(u32)inv[c];
        }
        bool qb1 = d21[j] <= tb1, qa1 = sm && d21[j] <= ta1;
        if (qb1 || qa1) {
            float d2v = __uint_as_float(d21[j]);
            float D = d2v > 0.0f ? __fsqrt_rn(d2v) : 0.0f;
            u64 hk = (u64)__float_as_uint(D) << 32;
            if (qb1 && cntB1 <= 256u) sbuf[1][ob1++] = hk | (u64)(u32)c;
            if (qa1 && cntA1 <= 256u) sbuf[3][oa1++] = hk | (u64)(u32)inv[c];
        }
    }
    __syncthreads();
    // per-wave sort + outputs
    int s = (wid & 1) ? s1 : s0;
    float4 q = (wid & 1) ? q1 : q0;
    u32 cnt = (wid == 0) ? cntB0 : (wid == 1) ? cntB1 : (wid == 2) ? cntA0 : cntA1;
    u64 res;
    if (wid < 2) {
        res = (cnt <= 256u) ? finalize_sort<4>(sbuf[wid], cnt, lane)
                            : cold_ladder<4, false>(q, cb, inv, lane);
        int idx = (int)(res & 0xffffffffull);
        if (lane < 4) a_before[s * 4 + lane] = idx;
        if (lane >= 1 && lane < 4)
            intra_before[s * 6 + (lane - 1)] = pair_dist_d(q, cb[idx]);
        int i1 = __shfl(idx, 1, 64);
        int i2 = __shfl(idx, 2, 64);
        int i3 = __shfl(idx, 3, 64);
        if (lane < 3) {  // pairs (1,2),(1,3),(2,3)
            int pa = (lane == 2) ? i2 : i1;
            int pb = (lane == 0) ? i2 : i3;
            intra_before[s * 6 + 3 + lane] = pair_dist_d(cb[pa], cb[pb]);
        }
    } else {
        res = (cnt <= 256u) ? finalize_sort<16>(sbuf[wid], cnt, lane)
                            : cold_ladder<16, true>(q, cb, inv, lane);
        int idx = (int)(res & 0xffffffffull);
        if (lane < 16) {
            ni_i[s * 16 + lane] = idx;
            out_ni[s * 16 + lane] = (float)idx;
        }
        if (lane >= 1 && lane < 4)
            intra_after[s * 6 + (lane - 1)] = pair_dist_d(q, ca[idx]);
        int i1 = __shfl(idx, 1, 64);
        int i2 = __shfl(idx, 2, 64);
        int i3 = __shfl(idx, 3, 64);
        if (lane < 3) {
            int pa = (lane == 2) ? i2 : i1;
            int pb = (lane == 0) ? i2 : i3;
            intra_after[s * 6 + 3 + lane] = pair_dist_d(ca[pa], ca[pb]);
        }
    }
}

// ---------------------------------------------------------------- assemble + mlp1 fused
// 4 samples per block (one wave each); then 28->128 linear for those samples.
__global__ __launch_bounds__(256) void asm_mlp1_kernel(
        const float4* __restrict__ ca, const float4* __restrict__ cb,
        const int* __restrict__ ni_i, const float* __restrict__ intra_after,
        const int* __restrict__ a_before, const float* __restrict__ intra_before,
        const int* __restrict__ sidx,
        const float* __restrict__ Ww, const float* __restrict__ bw,
        const float* __restrict__ Wb, const float* __restrict__ bb,
        float* __restrict__ out_rf, float* __restrict__ adf,
        float* __restrict__ y_wb) {
    __shared__ int s_ni[4][16];
    __shared__ float s_rf[4][16 * 28];
    __shared__ float s_ia[4][8];
    __shared__ float s_adf[4][28];
    __shared__ float sW[28 * 128];   // col c<64: Ww, else Wb
    __shared__ float sb[128];
    int t = threadIdx.x, wid = t >> 6, lane = t & 63;
    int s = blockIdx.x * 4 + wid;
    for (int i = t; i < 28 * 128; i += 256) {
        int k = i >> 7, c = i & 127;
        sW[i] = (c < 64) ? Ww[k * 64 + c] : Wb[k * 64 + (c - 64)];
    }
    if (t < 128) sb[t] = (t < 64) ? bw[t] : bb[t - 64];
    if (lane < 16) s_ni[wid][lane] = ni_i[s * 16 + lane];
    if (lane < 6) s_ia[wid][lane] = intra_after[s * 6 + lane];
    __syncthreads();

    // inter block of rf: rf[s,k,12+p*4+q] = D_after(ni[s,p], ni[ni[s,k],q])
    int k = lane >> 2, qq = lane & 3;
    int nai_q = ni_i[s_ni[wid][k] * 16 + qq];
    float4 pq = ca[nai_q];
#pragma unroll
    for (int p = 0; p < 4; ++p) {
        float4 pp = ca[s_ni[wid][p]];
        s_rf[wid][k * 28 + 12 + p * 4 + qq] = pair_dist_d(pp, pq);
    }
    // center intra (ch 0..5) + neighbor intra (ch 6..11)
    for (int idx = lane; idx < 16 * 12; idx += 64) {
        int kk = idx / 12, c = idx % 12;
        float v = (c < 6) ? s_ia[wid][c] : intra_after[s_ni[wid][kk] * 6 + (c - 6)];
        s_rf[wid][kk * 28 + c] = v;
    }
    // adf: [intra_before(6), intra_after(6), inter(16)] (also into LDS)
    if (lane < 16) {
        int p = lane >> 2, q2 = lane & 3;
        int ib = a_before[s * 4 + p];
        int ia = sidx[s_ni[wid][q2]];
        float v = pair_dist_d(cb[ib], cb[ia]);
        adf[s * 28 + 12 + lane] = v;
        s_adf[wid][12 + lane] = v;
    } else if (lane >= 32 && lane < 38) {
        float v = intra_before[s * 6 + (lane - 32)];
        adf[s * 28 + (lane - 32)] = v;
        s_adf[wid][lane - 32] = v;
    } else if (lane >= 40 && lane < 46) {
        float v = s_ia[wid][lane - 40];
        adf[s * 28 + 6 + (lane - 40)] = v;
        s_adf[wid][6 + (lane - 40)] = v;
    }
    const int base = s * 16 * 28;
    for (int idx = lane; idx < 16 * 28; idx += 64) out_rf[base + idx] = s_rf[wid][idx];
    __syncthreads();
    // mlp1: 4 samples x 128 channels = 512 outputs
    int s0 = blockIdx.x * 4;
#pragma unroll
    for (int o = t; o < 512; o += 256) {
        int r = o >> 7, c = o & 127;
        float acc = sb[c];
#pragma unroll
        for (int k2 = 0; k2 < 28; ++k2)
            acc = fmaf(s_adf[r][k2], sW[k2 * 128 + c], acc);
        y_wb[c * 4096 + s0 + r] = acc;
    }
}

// ---------------------------------------------------------------- batchnorm stats (stage 1 only)
__global__ __launch_bounds__(256) void stats_kernel(
        const float* __restrict__ y,  // [C][4096]
        const float* __restrict__ g0, const float* __restrict__ be0,
        const float* __restrict__ g1, const float* __restrict__ be1, int csplit,
        float* __restrict__ scale, float* __restrict__ shift) {
    int c = blockIdx.x;
    const float* p = y + c * 4096;
    float s1 = 0.0f, s2 = 0.0f;
    for (int i = threadIdx.x; i < 4096; i += 256) {
        float v = p[i];
        s1 += v;
        s2 = fmaf(v, v, s2);
    }
    __shared__ float l1[256], l2[256];
    l1[threadIdx.x] = s1;
    l2[threadIdx.x] = s2;
    __syncthreads();
    for (int off = 128; off; off >>= 1) {
        if (threadIdx.x < off) {
            l1[threadIdx.x] += l1[threadIdx.x + off];
            l2[threadIdx.x] += l2[threadIdx.x + off];
        }
        __syncthreads();
    }
    if (threadIdx.x == 0) {
        float mean = l1[0] * (1.0f / 4096.0f);
        float var = l2[0] * (1.0f / 4096.0f) - mean * mean;
        float g = (c < csplit) ? g0[c] : g1[c - csplit];
        float be = (c < csplit) ? be0[c] : be1[c - csplit];
        float sc = g / sqrtf(var + 1e-5f);
        scale[c] = sc;
        shift[c] = be - mean * sc;
    }
}

// ---------------------------------------------------------------- mlp2: f1 = lrelu(feat*w + b); y_o = [f1,adf]@Wo + bo
__global__ __launch_bounds__(256) void mlp2_kernel(
        const float* __restrict__ y_wb,
        const float* __restrict__ scale1, const float* __restrict__ shift1,
        const float* __restrict__ feature, const int* __restrict__ sidx,
        const float* __restrict__ adf,
        const float* __restrict__ Wo, const float* __restrict__ bo,
        float* __restrict__ y_o) {
    __shared__ float sW[92 * 128];       // 47104 B
    __shared__ float t2[16 * 129];       // padded staging
    __shared__ float scat[16 * 92];      // cat rows
    int t = threadIdx.x;
    int s0 = blockIdx.x * 16;
    for (int i = t; i < 92 * 128; i += 256) sW[i] = Wo[i];
    for (int i = t; i < 16 * 128; i += 256) {
        int row = i & 15, c = i >> 4;
        t2[row * 129 + c] = fmaf(y_wb[c * 4096 + s0 + row], scale1[c], shift1[c]);
    }
    __syncthreads();
    for (int rr = 0; rr < 16; rr += 4) {
        int r = rr + (t >> 6);
        int c = t & 63;
        int si = sidx[s0 + r];
        float f = feature[si * 64 + c];
        float v = fmaf(f, t2[r * 129 + c], t2[r * 129 + 64 + c]);
        scat[r * 92 + c] = v >= 0.0f ? v : 0.2f * v;
    }
    for (int i = t; i < 16 * 28; i += 256) {
        int row = i / 28, k = i % 28;
        scat[row * 92 + 64 + k] = adf[(s0 + row) * 28 + k];
    }
    __syncthreads();
    int r = t >> 4, cg = t & 15;
    float acc[8];
#pragma unroll
    for (int j = 0; j < 8; ++j) acc[j] = bo[cg * 8 + j];
    for (int c = 0; c < 92; ++c) {
        float a = scat[r * 92 + c];
#pragma unroll
        for (int j = 0; j < 8; ++j)
            acc[j] = fmaf(a, sW[c * 128 + cg * 8 + j], acc[j]);
    }
    int s = s0 + r;
#pragma unroll
    for (int j = 0; j < 8; ++j) y_o[(cg * 8 + j) * 4096 + s] = acc[j];
}

// ---------------------------------------------------------------- final: per-channel stats + normalize + lrelu
__global__ __launch_bounds__(256) void final_kernel(
        const float* __restrict__ y_o,
        const float* __restrict__ go, const float* __restrict__ betao,
        float* __restrict__ out_feat) {
    int j = blockIdx.x;
    const float* p = y_o + j * 4096;
    float s1 = 0.0f, s2 = 0.0f;
    for (int i = threadIdx.x; i < 4096; i += 256) {
        float v = p[i];
        s1 += v;
        s2 = fmaf(v, v, s2);
    }
    __shared__ float l1[256], l2[256];
    __shared__ float ssc, ssh;
    l1[threadIdx.x] = s1;
    l2[threadIdx.x] = s2;
    __syncthreads();
    for (int off = 128; off; off >>= 1) {
        if (threadIdx.x < off) {
            l1[threadIdx.x] += l1[threadIdx.x + off];
            l2[threadIdx.x] += l2[threadIdx.x + off];
        }
        __syncthreads();
    }
    if (threadIdx.x == 0) {
        float mean = l1[0] * (1.0f / 4096.0f);
        float var = l2[0] * (1.0f / 4096.0f) - mean * mean;
        float sc = go[j] / sqrtf(var + 1e-5f);
        ssc = sc;
        ssh = betao[j] - mean * sc;
    }
    __syncthreads();
    float sc = ssc, sh = ssh;
    for (int i = threadIdx.x; i < 4096; i += 256) {
        float v = fmaf(p[i], sc, sh);
        v = v >= 0.0f ? v : 0.2f * v;
        out_feat[i * 128 + j] = v;
    }
}

// ----------------------------------------------------------------
extern "C" void kernel_launch(void* const* d_in, const int* in_sizes, int n_in,
                              void* d_out, int out_size, void* d_ws, size_t ws_size,
                              hipStream_t stream) {
    const float* xyz = (const float*)d_in[0];
    const float* feature = (const float*)d_in[1];
    const int* sidx = (const int*)d_in[2];
    const float* Ww = (const float*)d_in[3];
    const float* bw = (const float*)d_in[4];
    const float* gw = (const float*)d_in[5];
    const float* betaw = (const float*)d_in[6];
    const float* Wb = (const float*)d_in[7];
    const float* bb = (const float*)d_in[8];
    const float* gb = (const float*)d_in[9];
    const float* betab = (const float*)d_in[10];
    const float* Wo = (const float*)d_in[11];
    const float* bo = (const float*)d_in[12];
    const float* go = (const float*)d_in[13];
    const float* betao = (const float*)d_in[14];

    float* out = (float*)d_out;
    float* out_xyz = out;                                  // 4096*3
    float* out_feat = out + 12288;                         // 4096*128
    float* out_rf = out + 12288 + 524288;                  // 4096*16*28
    float* out_ni = out + 12288 + 524288 + 1835008;        // 4096*16

    float* ws = (float*)d_ws;
    float4* cb = (float4*)ws;                  // 8192 float4
    float4* ca = (float4*)(ws + 32768);        // 4096 float4
    int* a_before = (int*)(ws + 49152);        // 4096*4
    float* intra_before = ws + 65536;          // 4096*6
    int* ni_i = (int*)(ws + 90112);            // 4096*16
    float* intra_after = ws + 155648;          // 4096*6
    float* adf = ws + 180224;                  // 4096*28
    float* y_wb = ws + 294912;                 // 128*4096
    float* y_o = ws + 819200;                  // 128*4096
    float* scale1 = ws + 1343488;              // 128
    float* shift1 = ws + 1343616;              // 128
    int* inv = (int*)(ws + 1343744);           // 8192 ints

    hipMemsetAsync(inv, 0xFF, N_PTS * sizeof(int), stream);
    stage_kernel<<<32, 256, 0, stream>>>(xyz, sidx, cb, ca, inv, out_xyz);
    knn_kernel<<<2048, 256, 0, stream>>>(cb, ca, inv, sidx, a_before, intra_before,
                                         ni_i, intra_after, out_ni);
    asm_mlp1_kernel<<<1024, 256, 0, stream>>>(ca, cb, ni_i, intra_after, a_before,
                                              intra_before, sidx, Ww, bw, Wb, bb,
                                              out_rf, adf, y_wb);
    stats_kernel<<<128, 256, 0, stream>>>(y_wb, gw, betaw, gb, betab, 64, scale1, shift1);
    mlp2_kernel<<<256, 256, 0, stream>>>(y_wb, scale1, shift1, feature, sidx, adf, Wo, bo, y_o);
    final_kernel<<<128, 256, 0, stream>>>(y_o, go, betao, out_feat);
}